// Round 16
// baseline (745.911 us; speedup 1.0000x reference)
//
#include <hip/hip_runtime.h>
#include <hip/hip_bf16.h>

using u16 = unsigned short;
typedef float f32x4 __attribute__((ext_vector_type(4)));
typedef short short8 __attribute__((ext_vector_type(8)));
typedef unsigned short ushort8 __attribute__((ext_vector_type(8)));

typedef __attribute__((address_space(1))) const unsigned int gu32;
typedef __attribute__((address_space(3))) unsigned int lu32;

__device__ __forceinline__ float b2f(u16 u) {
  unsigned v = ((unsigned)u) << 16;
  float f;
  __builtin_memcpy(&f, &v, 4);
  return f;
}
__device__ __forceinline__ u16 f2b(float f) {
  unsigned u;
  __builtin_memcpy(&u, &f, 4);
  unsigned r = (u + 0x7fffu + ((u >> 16) & 1u)) >> 16;
  return (u16)r;
}
__device__ __forceinline__ float ldv(float x) { return x; }
__device__ __forceinline__ float ldv(u16 x) { return b2f(x); }

__device__ __forceinline__ void gl_lds16(const void* g, void* l) {
  __builtin_amdgcn_global_load_lds((gu32*)g, (lu32*)l, 16, 0, 0);
}

// ---------------- row LayerNorm; input f32 or bf16, params f32, out bf16 -------
template <int D, bool RELU, bool PEREXP, typename TIN>
__global__ void ln_rows(const TIN* __restrict__ in, u16* __restrict__ out,
                        const float* __restrict__ gamma, const float* __restrict__ beta,
                        const int* __restrict__ pairExp, const int* __restrict__ total) {
  constexpr int T = (D >= 256) ? 256 : 64;
  constexpr int VPT = D / T;
  int row = blockIdx.x;
  if constexpr (PEREXP) {
    if (row >= *total) return;
  }
  int t = threadIdx.x;
  const TIN* r = in + (size_t)row * D;
  float vals[VPT];
  float s = 0.f, ss = 0.f;
#pragma unroll
  for (int i = 0; i < VPT; ++i) {
    float v = ldv(r[t + i * T]);
    vals[i] = v;
    s += v;
    ss += v * v;
  }
#pragma unroll
  for (int m = 1; m < 64; m <<= 1) {
    s += __shfl_xor(s, m);
    ss += __shfl_xor(ss, m);
  }
  if constexpr (T == 256) {
    __shared__ float red[8];
    int wave = t >> 6, lane = t & 63;
    if (lane == 0) { red[wave] = s; red[4 + wave] = ss; }
    __syncthreads();
    s = red[0] + red[1] + red[2] + red[3];
    ss = red[4] + red[5] + red[6] + red[7];
  }
  float mean = s / (float)D;
  float var = ss / (float)D - mean * mean;
  var = fmaxf(var, 0.f);
  float rstd = 1.f / sqrtf(var + 1e-5f);
  const float* g = gamma;
  const float* b = beta;
  if constexpr (PEREXP) {
    int e = pairExp[row];
    g += (size_t)e * D;
    b += (size_t)e * D;
  }
  u16* o = out + (size_t)row * D;
#pragma unroll
  for (int i = 0; i < VPT; ++i) {
    int idx = t + i * T;
    float v = (vals[i] - mean) * rstd * g[idx] + b[idx];
    if constexpr (RELU) v = fmaxf(v, 0.f);
    o[idx] = f2b(v);
  }
}

// ---------------- prepack: W f32 [K][M] -> bf16 [M][K], z-batched ----------------
__global__ void prepackT(const float* __restrict__ in, u16* __restrict__ out,
                         int K, int M) {
  __shared__ u16 tile[64 * 65];
  size_t zo = (size_t)blockIdx.z * K * M;
  const float* ip = in + zo;
  u16* op = out + zo;
  int m0 = blockIdx.x * 64, k0 = blockIdx.y * 64;
  int t = threadIdx.x;
#pragma unroll
  for (int h = 0; h < 4; ++h) {
    int u = t + h * 256;
    int kr = u >> 4, mc = (u & 15) * 4;
    f32x4 v = *(const f32x4*)(ip + (size_t)(k0 + kr) * M + m0 + mc);
#pragma unroll
    for (int i = 0; i < 4; ++i) tile[kr * 65 + mc + i] = f2b(v[i]);
  }
  __syncthreads();
#pragma unroll
  for (int h = 0; h < 2; ++h) {
    int u = t + h * 256;
    int mr = u >> 3, kc = (u & 7) * 8;
    ushort8 v;
#pragma unroll
    for (int i = 0; i < 8; ++i) v[i] = tile[(kc + i) * 65 + mr];
    *(ushort8*)(op + (size_t)(m0 + mr) * K + k0 + kc) = v;
  }
}

// ---------------- id_emb f32 -> xb3 cols 0..1023 (bf16) ----------------
__global__ void copy_id3(const float* __restrict__ id, u16* __restrict__ xb3) {
  size_t i = ((size_t)blockIdx.x * 256 + threadIdx.x) * 8;
  size_t t = i >> 10, d = i & 1023;
  f32x4 a = *(const f32x4*)(id + i);
  f32x4 b = *(const f32x4*)(id + i + 4);
  ushort8 v;
#pragma unroll
  for (int j = 0; j < 4; ++j) { v[j] = f2b(a[j]); v[j + 4] = f2b(b[j]); }
  *(ushort8*)(xb3 + t * 3072 + d) = v;
}

#define BM 128
#define BN 256
#define BK 32

// ---------------- GEMM: bf16 A [rows][lda], bf16 Bt [M][K] ----------------------
// 128x256 tile, 4 waves 1x4 (per-wave 128x64 = 8x4 frags): 12 LDS reads / 32 MFMA
// (vs 8/16 before) -> 1.33x higher LDS-BW ceiling. Depth-2 counted-vmcnt pipeline
// (R15-proven sync): wait vmcnt(6) while next tile's 6 loads stay in flight.
template <int EPI, bool EXPERT, bool GATHER>
__global__ __launch_bounds__(256, 2)
void gemm_bf(const u16* __restrict__ A, const u16* __restrict__ Bt,
             const float* __restrict__ bias,
             u16* __restrict__ C, float* __restrict__ Cf,
             int K, int lda, int ldc,
             long strideB, int strideBias,
             const int* __restrict__ offA, const int* __restrict__ pairTok,
             const float* __restrict__ resid, const float* __restrict__ alphaPtr) {
  int rowTile = blockIdx.x * BM;
  int colTile = blockIdx.y * BN;
  if constexpr (EXPERT) {
    if (rowTile >= offA[8]) return;
    int e = 0;
    while (rowTile >= offA[e + 1]) ++e;  // <=8 uniform iters
    Bt += (size_t)e * strideB;
    bias += (size_t)e * strideBias;
  }

  __shared__ u16 As[2][BM * BK];  // 2 x 8 KB
  __shared__ u16 Bs[2][BN * BK];  // 2 x 16 KB

  int t = threadIdx.x;
  int lane = t & 63;
  int wv = t >> 6;  // wave owns cols [wv*64, wv*64+64)
  int l15 = lane & 15, l4 = lane >> 4;

  // ---- staging: A = 8 chunks (16 rows x 32 cols = 1KB); wave stages {wv, wv+4}.
  //      B = 16 chunks; wave stages {4wv..4wv+3}. lane covers row c*16+(lane>>2),
  //      col (lane&3)*8; LDS dest = chunk base + lane*16B (linear identity).
  int rIn = lane >> 2, cIn = (lane & 3) * 8;
  int ca0 = wv, ca1 = wv + 4;
  size_t aRow0, aRow1;
  if constexpr (GATHER) {
    aRow0 = (size_t)pairTok[rowTile + ca0 * 16 + rIn] * lda;
    aRow1 = (size_t)pairTok[rowTile + ca1 * 16 + rIn] * lda;
  } else {
    aRow0 = (size_t)(rowTile + ca0 * 16 + rIn) * lda;
    aRow1 = (size_t)(rowTile + ca1 * 16 + rIn) * lda;
  }
  const u16* aSrc0 = A + aRow0 + cIn;
  const u16* aSrc1 = A + aRow1 + cIn;
  const u16* bSrc[4];
#pragma unroll
  for (int i = 0; i < 4; ++i) {
    int cb = 4 * wv + i;
    bSrc[i] = Bt + (size_t)(colTile + cb * 16 + rIn) * K + cIn;
  }

  auto STAGE = [&](int k0, int b) {
    gl_lds16(aSrc0 + k0, &As[b][ca0 * 512]);
    gl_lds16(aSrc1 + k0, &As[b][ca1 * 512]);
#pragma unroll
    for (int i = 0; i < 4; ++i) gl_lds16(bSrc[i] + k0, &Bs[b][(4 * wv + i) * 512]);
  };

  f32x4 zero4 = {0.f, 0.f, 0.f, 0.f};
  f32x4 acc[8][4];
#pragma unroll
  for (int m = 0; m < 8; ++m)
#pragma unroll
    for (int n = 0; n < 4; ++n) acc[m][n] = zero4;

  int nt = K / BK;
  STAGE(0, 0);
  if (nt > 1) STAGE(BK, 1);

  for (int tt = 0; tt < nt; ++tt) {
    if (nt - tt >= 2)
      asm volatile("s_waitcnt vmcnt(6)" ::: "memory");  // tile tt's 6 loads done
    else
      asm volatile("s_waitcnt vmcnt(0)" ::: "memory");
    __syncthreads();  // all waves' tile-tt chunks visible
    int cur = tt & 1;
    short8 af[8], bf[4];
#pragma unroll
    for (int m = 0; m < 8; ++m)
      af[m] = *(const short8*)&As[cur][(m * 16 + l15) * BK + l4 * 8];
#pragma unroll
    for (int n = 0; n < 4; ++n)
      bf[n] = *(const short8*)&Bs[cur][(wv * 64 + n * 16 + l15) * BK + l4 * 8];
#pragma unroll
    for (int m = 0; m < 8; ++m)
#pragma unroll
      for (int n = 0; n < 4; ++n)
        acc[m][n] = __builtin_amdgcn_mfma_f32_16x16x32_bf16(af[m], bf[n], acc[m][n], 0, 0, 0);
    __syncthreads();  // all waves done reading buf[cur]
    if (tt + 2 < nt) STAGE((tt + 2) * BK, cur);  // refill freed buffer, async
  }

  float alphaV = 0.f;
  if constexpr (EPI == 2) alphaV = alphaPtr[0];
#pragma unroll
  for (int n = 0; n < 4; ++n) {
    int col = colTile + wv * 64 + n * 16 + l15;
    float bv = bias[col];
#pragma unroll
    for (int m = 0; m < 8; ++m) {
      int r2 = rowTile + m * 16 + l4 * 4;
#pragma unroll
      for (int j = 0; j < 4; ++j) {
        float v = acc[m][n][j] + bv;
        if constexpr (EPI == 1) v = fmaxf(v, 0.f);
        if constexpr (EPI == 2) {
          Cf[(size_t)(r2 + j) * ldc + col] =
              resid[(size_t)(r2 + j) * ldc + col] + alphaV * v;
        } else {
          C[(size_t)(r2 + j) * ldc + col] = f2b(v);
        }
      }
    }
  }
}

// ---------------- router: logits -> softmax -> top2 -> weights ----------------
__global__ void router_kernel(const u16* __restrict__ g2, const float* __restrict__ Wg3,
                              const float* __restrict__ bg3, float* __restrict__ probs,
                              int* __restrict__ topi, float* __restrict__ wts) {
  int tok = blockIdx.x * 4 + (threadIdx.x >> 6);
  int lane = threadIdx.x & 63;
  const u16* row = g2 + (size_t)tok * 768;
  float acc[8];
#pragma unroll
  for (int e = 0; e < 8; ++e) acc[e] = 0.f;
  for (int j = lane; j < 768; j += 64) {
    float v = b2f(row[j]);
    f32x4 w0 = *(const f32x4*)(Wg3 + (size_t)j * 8);
    f32x4 w1 = *(const f32x4*)(Wg3 + (size_t)j * 8 + 4);
#pragma unroll
    for (int e = 0; e < 4; ++e) { acc[e] += v * w0[e]; acc[e + 4] += v * w1[e]; }
  }
#pragma unroll
  for (int e = 0; e < 8; ++e) {
#pragma unroll
    for (int m = 1; m < 64; m <<= 1) acc[e] += __shfl_xor(acc[e], m);
  }
  if (lane == 0) {
    float lg[8], mx = -3.4e38f;
#pragma unroll
    for (int e = 0; e < 8; ++e) {
      lg[e] = acc[e] + bg3[e];
      mx = fmaxf(mx, lg[e]);
    }
    float p[8], s = 0.f;
#pragma unroll
    for (int e = 0; e < 8; ++e) {
      p[e] = expf(lg[e] - mx);
      s += p[e];
    }
    float inv = 1.f / s;
#pragma unroll
    for (int e = 0; e < 8; ++e) {
      p[e] *= inv;
      probs[(size_t)tok * 8 + e] = p[e];
    }
    int i0 = 0;
    for (int e = 1; e < 8; ++e)
      if (p[e] > p[i0]) i0 = e;
    int i1 = (i0 == 0) ? 1 : 0;
    for (int e = 0; e < 8; ++e)
      if (e != i0 && p[e] > p[i1]) i1 = e;
    float w0 = p[i0], w1 = p[i1];
    float wsum = w0 + w1 + 1e-8f;
    topi[tok * 2] = i0;
    topi[tok * 2 + 1] = i1;
    wts[tok * 2] = w0 / wsum;
    wts[tok * 2 + 1] = w1 / wsum;
  }
}

// ---------------- routing bookkeeping ----------------
__global__ void count_kernel(const int* __restrict__ topi, int* __restrict__ cnt,
                             int* __restrict__ offA, int* __restrict__ cursor) {
  __shared__ int c[8];
  int t = threadIdx.x;
  if (t < 8) c[t] = 0;
  __syncthreads();
  for (int i = t; i < 16384; i += 256) atomicAdd(&c[topi[i]], 1);
  __syncthreads();
  if (t == 0) {
    int off = 0;
    for (int e = 0; e < 8; ++e) {
      cnt[e] = c[e];
      offA[e] = off;
      cursor[e] = off;
      off += (c[e] + 127) & ~127;
    }
    offA[8] = off;
  }
}

__global__ void scatter_kernel(const int* __restrict__ topi, int* __restrict__ cursor,
                               int* __restrict__ pairTok, int* __restrict__ pairExp,
                               int* __restrict__ posOf) {
  int i = blockIdx.x * 256 + threadIdx.x;
  int e = topi[i];
  int pos = atomicAdd(&cursor[e], 1);
  pairTok[pos] = i >> 1;
  pairExp[pos] = e;
  posOf[i] = pos;
}

__global__ void padfill_kernel(const int* __restrict__ cnt, const int* __restrict__ offA,
                               int* __restrict__ pairTok, int* __restrict__ pairExp) {
  int e = blockIdx.x;
  int start = offA[e] + cnt[e];
  int end = offA[e + 1];
  for (int i = start + threadIdx.x; i < end; i += 256) {
    pairTok[i] = 0;
    pairExp[i] = e;
  }
}

// ---------------- combine top-2 expert outputs ----------------
__global__ void combine_kernel(const u16* __restrict__ eo, const int* __restrict__ posOf,
                               const float* __restrict__ wts, u16* __restrict__ comb) {
  int t = blockIdx.x, d = threadIdx.x;
  int p0 = posOf[t * 2], p1 = posOf[t * 2 + 1];
  float w0 = wts[t * 2], w1 = wts[t * 2 + 1];
  float v = w0 * b2f(eo[(size_t)p0 * 256 + d]) + w1 * b2f(eo[(size_t)p1 * 256 + d]);
  comb[(size_t)t * 256 + d] = f2b(v);
}

// ---------------- load-balance loss (f32 out) ----------------
__global__ void lbloss_kernel(const float* __restrict__ probs, const int* __restrict__ cnt,
                              float* __restrict__ outp) {
  __shared__ float red[256];
  int t = threadIdx.x;
  float pl[8];
#pragma unroll
  for (int e = 0; e < 8; ++e) pl[e] = 0.f;
  for (int i = t; i < 8192; i += 256) {
#pragma unroll
    for (int e = 0; e < 8; ++e) pl[e] += probs[(size_t)i * 8 + e];
  }
  float P[8];
  for (int e = 0; e < 8; ++e) {
    red[t] = pl[e];
    __syncthreads();
    for (int s = 128; s > 0; s >>= 1) {
      if (t < s) red[t] += red[t + s];
      __syncthreads();
    }
    P[e] = red[0] / 8192.f;
    __syncthreads();
  }
  if (t == 0) {
    float imp = 0.f, ent = 0.f;
    for (int e = 0; e < 8; ++e) {
      float f = (float)cnt[e] / 8192.f;
      imp += f * P[e];
      ent -= P[e] * logf(P[e] + 1e-8f);
    }
    imp *= 8.f;
    float maxent = logf(8.f);
    outp[0] = (imp + (maxent - ent) / maxent) * 0.01f;
  }
}

// =========================================================================
extern "C" void kernel_launch(void* const* d_in, const int* in_sizes, int n_in,
                              void* d_out, int out_size, void* d_ws, size_t ws_size,
                              hipStream_t stream) {
  const float* id_emb   = (const float*)d_in[0];
  const float* content  = (const float*)d_in[1];
  const float* collab   = (const float*)d_in[2];
  const float* ln_ct_g  = (const float*)d_in[3];
  const float* ln_ct_b  = (const float*)d_in[4];
  const float* ln_cb_g  = (const float*)d_in[5];
  const float* ln_cb_b  = (const float*)d_in[6];
  const float* Wc       = (const float*)d_in[7];
  const float* bc       = (const float*)d_in[8];
  const float* Wcb      = (const float*)d_in[9];
  const float* bcb      = (const float*)d_in[10];
  const float* Wg1      = (const float*)d_in[11];
  const float* bg1      = (const float*)d_in[12];
  const float* lng_g    = (const float*)d_in[13];
  const float* lng_b    = (const float*)d_in[14];
  const float* Wg2      = (const float*)d_in[15];
  const float* bg2      = (const float*)d_in[16];
  const float* Wg3      = (const float*)d_in[17];
  const float* bg3      = (const float*)d_in[18];
  const float* We1      = (const float*)d_in[19];
  const float* be1      = (const float*)d_in[20];
  const float* lne1_g   = (const float*)d_in[21];
  const float* lne1_b   = (const float*)d_in[22];
  const float* We2      = (const float*)d_in[23];
  const float* be2      = (const float*)d_in[24];
  const float* We3      = (const float*)d_in[25];
  const float* be3      = (const float*)d_in[26];
  const float* lne3_g   = (const float*)d_in[27];
  const float* lne3_b   = (const float*)d_in[28];
  const float* Wout     = (const float*)d_in[29];
  const float* bout     = (const float*)d_in[30];
  const float* alpha    = (const float*)d_in[31];
  (void)in_sizes; (void)n_in; (void)out_size; (void)ws_size;

  float* out = (float*)d_out;  // f32: 8388608 fused + 1 lb_loss
  char* ws = (char*)d_ws;
  size_t o = 0;
  auto AL = [&](size_t bytes) {
    size_t r = o;
    o += (bytes + 255) & ~(size_t)255;
    return r;
  };

  u16* WcT   = (u16*)(ws + AL(1024ull * 768 * 2));
  u16* WcbT  = (u16*)(ws + AL(1024ull * 64 * 2));
  u16* Wg1T  = (u16*)(ws + AL(1536ull * 3072 * 2));
  u16* Wg2T  = (u16*)(ws + AL(768ull * 1536 * 2));
  u16* We1T  = (u16*)(ws + AL(8ull * 1024 * 3072 * 2));
  u16* We2T  = (u16*)(ws + AL(8ull * 512 * 1024 * 2));
  u16* We3T  = (u16*)(ws + AL(8ull * 256 * 512 * 2));
  u16* WoutT = (u16*)(ws + AL(1024ull * 256 * 2));
  u16* xb3   = (u16*)(ws + AL(8192ull * 3072 * 2));
  size_t R1  = AL(17408ull * 1024 * 2);  // ct_norm|cb_norm -> g1 -> h1
  u16* ct_norm = (u16*)(ws + R1);
  u16* cb_norm = (u16*)(ws + R1 + 8192ull * 768 * 2);
  u16* g1      = (u16*)(ws + R1);
  u16* h1      = (u16*)(ws + R1);
  size_t R2  = AL(17408ull * 512 * 2);   // g2 -> h2
  u16* g2 = (u16*)(ws + R2);
  u16* h2 = (u16*)(ws + R2);
  u16* eo   = (u16*)(ws + AL(17408ull * 256 * 2));
  u16* comb = (u16*)(ws + AL(8192ull * 256 * 2));
  float* probs = (float*)(ws + AL(8192ull * 8 * 4));
  int* topi    = (int*)(ws + AL(8192ull * 2 * 4));
  float* wts   = (float*)(ws + AL(8192ull * 2 * 4));
  int* posOf   = (int*)(ws + AL(8192ull * 2 * 4));
  int* pairTok = (int*)(ws + AL(17408ull * 4));
  int* pairExp = (int*)(ws + AL(17408ull * 4));
  int* cnt     = (int*)(ws + AL(64));
  int* offA    = (int*)(ws + AL(64));
  int* cursor  = (int*)(ws + AL(64));

  // ---- weight prepack f32 [K][M] -> bf16 [M][K] ----
  prepackT<<<dim3(16, 12), 256, 0, stream>>>(Wc, WcT, 768, 1024);
  prepackT<<<dim3(16, 1), 256, 0, stream>>>(Wcb, WcbT, 64, 1024);
  prepackT<<<dim3(24, 48), 256, 0, stream>>>(Wg1, Wg1T, 3072, 1536);
  prepackT<<<dim3(12, 24), 256, 0, stream>>>(Wg2, Wg2T, 1536, 768);
  prepackT<<<dim3(16, 48, 8), 256, 0, stream>>>(We1, We1T, 3072, 1024);
  prepackT<<<dim3(8, 16, 8), 256, 0, stream>>>(We2, We2T, 1024, 512);
  prepackT<<<dim3(4, 8, 8), 256, 0, stream>>>(We3, We3T, 512, 256);
  prepackT<<<dim3(16, 4), 256, 0, stream>>>(Wout, WoutT, 256, 1024);

  // ---- input LN + build xb3 = [id | ct_proj | cb_proj] ----
  ln_rows<768, false, false, float><<<8192, 256, 0, stream>>>(content, ct_norm, ln_ct_g, ln_ct_b, nullptr, nullptr);
  ln_rows<64, false, false, float><<<8192, 64, 0, stream>>>(collab, cb_norm, ln_cb_g, ln_cb_b, nullptr, nullptr);
  copy_id3<<<4096, 256, 0, stream>>>(id_emb, xb3);
  gemm_bf<0, false, false><<<dim3(64, 4), 256, 0, stream>>>(
      ct_norm, WcT, bc, xb3 + 1024, nullptr, 768, 768, 3072,
      0, 0, nullptr, nullptr, nullptr, nullptr);
  gemm_bf<0, false, false><<<dim3(64, 4), 256, 0, stream>>>(
      cb_norm, WcbT, bcb, xb3 + 2048, nullptr, 64, 64, 3072,
      0, 0, nullptr, nullptr, nullptr, nullptr);

  // ---- router MLP ----
  gemm_bf<0, false, false><<<dim3(64, 6), 256, 0, stream>>>(
      xb3, Wg1T, bg1, g1, nullptr, 3072, 3072, 1536,
      0, 0, nullptr, nullptr, nullptr, nullptr);
  ln_rows<1536, true, false, u16><<<8192, 256, 0, stream>>>(g1, g1, lng_g, lng_b, nullptr, nullptr);
  gemm_bf<1, false, false><<<dim3(64, 3), 256, 0, stream>>>(
      g1, Wg2T, bg2, g2, nullptr, 1536, 1536, 768,
      0, 0, nullptr, nullptr, nullptr, nullptr);
  router_kernel<<<2048, 256, 0, stream>>>(g2, Wg3, bg3, probs, topi, wts);

  // ---- routing lists ----
  count_kernel<<<1, 256, 0, stream>>>(topi, cnt, offA, cursor);
  scatter_kernel<<<64, 256, 0, stream>>>(topi, cursor, pairTok, pairExp, posOf);
  padfill_kernel<<<8, 256, 0, stream>>>(cnt, offA, pairTok, pairExp);

  // ---- experts (top-2 grouped) ----
  gemm_bf<0, true, true><<<dim3(136, 4), 256, 0, stream>>>(
      xb3, We1T, be1, h1, nullptr, 3072, 3072, 1024,
      3072l * 1024, 1024, offA, pairTok, nullptr, nullptr);
  ln_rows<1024, true, true, u16><<<17408, 256, 0, stream>>>(h1, h1, lne1_g, lne1_b, pairExp, offA + 8);
  gemm_bf<1, true, false><<<dim3(136, 2), 256, 0, stream>>>(
      h1, We2T, be2, h2, nullptr, 1024, 1024, 512,
      512l * 1024, 512, offA, nullptr, nullptr, nullptr);
  gemm_bf<0, true, false><<<dim3(136, 1), 256, 0, stream>>>(
      h2, We3T, be3, eo, nullptr, 512, 512, 256,
      256l * 512, 256, offA, nullptr, nullptr, nullptr);
  ln_rows<256, false, true, u16><<<17408, 256, 0, stream>>>(eo, eo, lne3_g, lne3_b, pairExp, offA + 8);
  combine_kernel<<<8192, 256, 0, stream>>>(eo, posOf, wts, comb);

  // ---- output projection + alpha-residual -> f32 out ----
  gemm_bf<2, false, false><<<dim3(64, 4), 256, 0, stream>>>(
      comb, WoutT, bout, nullptr, out, 256, 256, 1024,
      0, 0, nullptr, nullptr, id_emb, alpha);

  // ---- load-balance loss (f32) ----
  lbloss_kernel<<<1, 256, 0, stream>>>(probs, cnt, out + 8388608);
}

// Round 17
// 644.335 us; speedup vs baseline: 1.1576x; 1.1576x over previous
//
#include <hip/hip_runtime.h>
#include <hip/hip_bf16.h>

using u16 = unsigned short;
typedef float f32x4 __attribute__((ext_vector_type(4)));
typedef short short8 __attribute__((ext_vector_type(8)));
typedef unsigned short ushort8 __attribute__((ext_vector_type(8)));

typedef __attribute__((address_space(1))) const unsigned int gu32;
typedef __attribute__((address_space(3))) unsigned int lu32;

__device__ __forceinline__ float b2f(u16 u) {
  unsigned v = ((unsigned)u) << 16;
  float f;
  __builtin_memcpy(&f, &v, 4);
  return f;
}
__device__ __forceinline__ u16 f2b(float f) {
  unsigned u;
  __builtin_memcpy(&u, &f, 4);
  unsigned r = (u + 0x7fffu + ((u >> 16) & 1u)) >> 16;
  return (u16)r;
}
__device__ __forceinline__ float ldv(float x) { return x; }
__device__ __forceinline__ float ldv(u16 x) { return b2f(x); }

__device__ __forceinline__ void gl_lds16(const void* g, void* l) {
  __builtin_amdgcn_global_load_lds((gu32*)g, (lu32*)l, 16, 0, 0);
}

// ---------------- row LayerNorm; input f32 or bf16, params f32, out bf16 -------
template <int D, bool RELU, bool PEREXP, typename TIN>
__global__ void ln_rows(const TIN* __restrict__ in, u16* __restrict__ out,
                        const float* __restrict__ gamma, const float* __restrict__ beta,
                        const int* __restrict__ pairExp, const int* __restrict__ total) {
  constexpr int T = (D >= 256) ? 256 : 64;
  constexpr int VPT = D / T;
  int row = blockIdx.x;
  if constexpr (PEREXP) {
    if (row >= *total) return;
  }
  int t = threadIdx.x;
  const TIN* r = in + (size_t)row * D;
  float vals[VPT];
  float s = 0.f, ss = 0.f;
#pragma unroll
  for (int i = 0; i < VPT; ++i) {
    float v = ldv(r[t + i * T]);
    vals[i] = v;
    s += v;
    ss += v * v;
  }
#pragma unroll
  for (int m = 1; m < 64; m <<= 1) {
    s += __shfl_xor(s, m);
    ss += __shfl_xor(ss, m);
  }
  if constexpr (T == 256) {
    __shared__ float red[8];
    int wave = t >> 6, lane = t & 63;
    if (lane == 0) { red[wave] = s; red[4 + wave] = ss; }
    __syncthreads();
    s = red[0] + red[1] + red[2] + red[3];
    ss = red[4] + red[5] + red[6] + red[7];
  }
  float mean = s / (float)D;
  float var = ss / (float)D - mean * mean;
  var = fmaxf(var, 0.f);
  float rstd = 1.f / sqrtf(var + 1e-5f);
  const float* g = gamma;
  const float* b = beta;
  if constexpr (PEREXP) {
    int e = pairExp[row];
    g += (size_t)e * D;
    b += (size_t)e * D;
  }
  u16* o = out + (size_t)row * D;
#pragma unroll
  for (int i = 0; i < VPT; ++i) {
    int idx = t + i * T;
    float v = (vals[i] - mean) * rstd * g[idx] + b[idx];
    if constexpr (RELU) v = fmaxf(v, 0.f);
    o[idx] = f2b(v);
  }
}

// ---------------- batched prepack: all weights f32 [K][M] -> bf16 [M][K] --------
struct PackDesc {
  const float* src;
  u16* dst;
  int K, M, tx, tilesPerMat, base;  // tx = tiles along M; z-batch folded in
};
struct PackTable { PackDesc d[8]; int total; };

__global__ void prepack_all(PackTable tab) {
  int bid = blockIdx.x;
  int w = 0;
#pragma unroll
  for (int i = 1; i < 8; ++i)
    if (bid >= tab.d[i].base) w = i;
  PackDesc pd = tab.d[w];
  int local = bid - pd.base;
  int z = local / pd.tilesPerMat;
  int tl = local % pd.tilesPerMat;
  int m0 = (tl % pd.tx) * 64, k0 = (tl / pd.tx) * 64;
  size_t zo = (size_t)z * pd.K * pd.M;
  const float* ip = pd.src + zo;
  u16* op = pd.dst + zo;

  __shared__ u16 tile[64 * 65];
  int t = threadIdx.x;
#pragma unroll
  for (int h = 0; h < 4; ++h) {
    int u = t + h * 256;
    int kr = u >> 4, mc = (u & 15) * 4;
    f32x4 v = *(const f32x4*)(ip + (size_t)(k0 + kr) * pd.M + m0 + mc);
#pragma unroll
    for (int i = 0; i < 4; ++i) tile[kr * 65 + mc + i] = f2b(v[i]);
  }
  __syncthreads();
#pragma unroll
  for (int h = 0; h < 2; ++h) {
    int u = t + h * 256;
    int mr = u >> 3, kc = (u & 7) * 8;
    ushort8 v;
#pragma unroll
    for (int i = 0; i < 8; ++i) v[i] = tile[(kc + i) * 65 + mr];
    *(ushort8*)(op + (size_t)(m0 + mr) * pd.K + k0 + kc) = v;
  }
}

// ---------------- id_emb f32 -> xb3 cols 0..1023 (bf16) ----------------
__global__ void copy_id3(const float* __restrict__ id, u16* __restrict__ xb3) {
  size_t i = ((size_t)blockIdx.x * 256 + threadIdx.x) * 8;
  size_t t = i >> 10, d = i & 1023;
  f32x4 a = *(const f32x4*)(id + i);
  f32x4 b = *(const f32x4*)(id + i + 4);
  ushort8 v;
#pragma unroll
  for (int j = 0; j < 4; ++j) { v[j] = f2b(a[j]); v[j + 4] = f2b(b[j]); }
  *(ushort8*)(xb3 + t * 3072 + d) = v;
}

#define BM 128
#define BN 128
#define BKK 64

// ---------------- GEMM: bf16 A [rows][lda], bf16 Bt [M][K]; BK=64 single-buffer
// (R13 structure, natural raster — best measured We1; 12 barrier drains/K-loop).
template <int EPI, bool EXPERT, bool GATHER>
__global__ __launch_bounds__(256, 3)
void gemm_bf(const u16* __restrict__ A, const u16* __restrict__ Bt,
             const float* __restrict__ bias,
             u16* __restrict__ C, float* __restrict__ Cf,
             int K, int lda, int ldc,
             long strideB, int strideBias,
             const int* __restrict__ offA, const int* __restrict__ pairTok,
             const float* __restrict__ resid, const float* __restrict__ alphaPtr) {
  int rowTile = blockIdx.x * BM;
  int colTile = blockIdx.y * BN;
  if constexpr (EXPERT) {
    if (rowTile >= offA[8]) return;
    int e = 0;
    while (rowTile >= offA[e + 1]) ++e;  // <=8 uniform iters
    Bt += (size_t)e * strideB;
    bias += (size_t)e * strideBias;
  }

  __shared__ u16 As[BM * BKK];  // 16 KB
  __shared__ u16 Bs[BN * BKK];  // 16 KB

  int t = threadIdx.x;
  int lane = t & 63;
  int wv = t >> 6;
  int wr = wv >> 1, wc = wv & 1;
  int l15 = lane & 15, l4 = lane >> 4;

  // staging: round j in 0..3, wave wv: rows j*32 + wv*8 + (lane>>3), col (lane&7)*8.
  // LDS dest = wave-uniform chunk base + lane*16B (linear [row][64]).
  int rowInLane = lane >> 3;
  int colLane = (lane & 7) * 8;
  const u16* aSrc[4];
  const u16* bSrc[4];
  u16* aDst[4];
  u16* bDst[4];
#pragma unroll
  for (int j = 0; j < 4; ++j) {
    int rr = j * 32 + wv * 8 + rowInLane;
    size_t aRow;
    if constexpr (GATHER) {
      aRow = (size_t)pairTok[rowTile + rr] * lda;
    } else {
      aRow = (size_t)(rowTile + rr) * lda;
    }
    aSrc[j] = A + aRow + colLane;
    bSrc[j] = Bt + (size_t)(colTile + rr) * K + colLane;
    aDst[j] = As + (j * 32 + wv * 8) * BKK;
    bDst[j] = Bs + (j * 32 + wv * 8) * BKK;
  }

  f32x4 zero4 = {0.f, 0.f, 0.f, 0.f};
  f32x4 acc[4][4];
#pragma unroll
  for (int m = 0; m < 4; ++m)
#pragma unroll
    for (int n = 0; n < 4; ++n) acc[m][n] = zero4;

  for (int k0 = 0; k0 < K; k0 += BKK) {
    __syncthreads();
#pragma unroll
    for (int j = 0; j < 4; ++j) gl_lds16(aSrc[j] + k0, aDst[j]);
#pragma unroll
    for (int j = 0; j < 4; ++j) gl_lds16(bSrc[j] + k0, bDst[j]);
    asm volatile("s_waitcnt vmcnt(0)" ::: "memory");
    __syncthreads();
    short8 af[4][2];
#pragma unroll
    for (int m = 0; m < 4; ++m)
#pragma unroll
      for (int ks = 0; ks < 2; ++ks)
        af[m][ks] = *(const short8*)&As[(wr * 64 + m * 16 + l15) * BKK + ks * 32 + l4 * 8];
#pragma unroll
    for (int n = 0; n < 4; ++n) {
      short8 bfr[2];
#pragma unroll
      for (int ks = 0; ks < 2; ++ks)
        bfr[ks] = *(const short8*)&Bs[(wc * 64 + n * 16 + l15) * BKK + ks * 32 + l4 * 8];
#pragma unroll
      for (int m = 0; m < 4; ++m)
#pragma unroll
        for (int ks = 0; ks < 2; ++ks)  // ks ascending: bit-identical order
          acc[m][n] = __builtin_amdgcn_mfma_f32_16x16x32_bf16(af[m][ks], bfr[ks], acc[m][n], 0, 0, 0);
    }
  }

  float alphaV = 0.f;
  if constexpr (EPI == 2) alphaV = alphaPtr[0];
#pragma unroll
  for (int n = 0; n < 4; ++n) {
    int col = colTile + wc * 64 + n * 16 + l15;
    float bv = bias[col];
#pragma unroll
    for (int m = 0; m < 4; ++m) {
      int r2 = rowTile + wr * 64 + m * 16 + l4 * 4;
#pragma unroll
      for (int j = 0; j < 4; ++j) {
        float v = acc[m][n][j] + bv;
        if constexpr (EPI == 1) v = fmaxf(v, 0.f);
        if constexpr (EPI == 2) {
          Cf[(size_t)(r2 + j) * ldc + col] =
              resid[(size_t)(r2 + j) * ldc + col] + alphaV * v;
        } else {
          C[(size_t)(r2 + j) * ldc + col] = f2b(v);
        }
      }
    }
  }
}

// ---------------- router: logits -> softmax -> top2 -> weights ----------------
__global__ void router_kernel(const u16* __restrict__ g2, const float* __restrict__ Wg3,
                              const float* __restrict__ bg3, float* __restrict__ probs,
                              int* __restrict__ topi, float* __restrict__ wts) {
  int tok = blockIdx.x * 4 + (threadIdx.x >> 6);
  int lane = threadIdx.x & 63;
  const u16* row = g2 + (size_t)tok * 768;
  float acc[8];
#pragma unroll
  for (int e = 0; e < 8; ++e) acc[e] = 0.f;
  for (int j = lane; j < 768; j += 64) {
    float v = b2f(row[j]);
    f32x4 w0 = *(const f32x4*)(Wg3 + (size_t)j * 8);
    f32x4 w1 = *(const f32x4*)(Wg3 + (size_t)j * 8 + 4);
#pragma unroll
    for (int e = 0; e < 4; ++e) { acc[e] += v * w0[e]; acc[e + 4] += v * w1[e]; }
  }
#pragma unroll
  for (int e = 0; e < 8; ++e) {
#pragma unroll
    for (int m = 1; m < 64; m <<= 1) acc[e] += __shfl_xor(acc[e], m);
  }
  if (lane == 0) {
    float lg[8], mx = -3.4e38f;
#pragma unroll
    for (int e = 0; e < 8; ++e) {
      lg[e] = acc[e] + bg3[e];
      mx = fmaxf(mx, lg[e]);
    }
    float p[8], s = 0.f;
#pragma unroll
    for (int e = 0; e < 8; ++e) {
      p[e] = expf(lg[e] - mx);
      s += p[e];
    }
    float inv = 1.f / s;
#pragma unroll
    for (int e = 0; e < 8; ++e) {
      p[e] *= inv;
      probs[(size_t)tok * 8 + e] = p[e];
    }
    int i0 = 0;
    for (int e = 1; e < 8; ++e)
      if (p[e] > p[i0]) i0 = e;
    int i1 = (i0 == 0) ? 1 : 0;
    for (int e = 0; e < 8; ++e)
      if (e != i0 && p[e] > p[i1]) i1 = e;
    float w0 = p[i0], w1 = p[i1];
    float wsum = w0 + w1 + 1e-8f;
    topi[tok * 2] = i0;
    topi[tok * 2 + 1] = i1;
    wts[tok * 2] = w0 / wsum;
    wts[tok * 2 + 1] = w1 / wsum;
  }
}

// ---------------- routing bookkeeping ----------------
__global__ void count_kernel(const int* __restrict__ topi, int* __restrict__ cnt,
                             int* __restrict__ offA, int* __restrict__ cursor) {
  __shared__ int c[8];
  int t = threadIdx.x;
  if (t < 8) c[t] = 0;
  __syncthreads();
  for (int i = t; i < 16384; i += 256) atomicAdd(&c[topi[i]], 1);
  __syncthreads();
  if (t == 0) {
    int off = 0;
    for (int e = 0; e < 8; ++e) {
      cnt[e] = c[e];
      offA[e] = off;
      cursor[e] = off;
      off += (c[e] + 127) & ~127;
    }
    offA[8] = off;
  }
}

__global__ void scatter_kernel(const int* __restrict__ topi, int* __restrict__ cursor,
                               int* __restrict__ pairTok, int* __restrict__ pairExp,
                               int* __restrict__ posOf) {
  int i = blockIdx.x * 256 + threadIdx.x;
  int e = topi[i];
  int pos = atomicAdd(&cursor[e], 1);
  pairTok[pos] = i >> 1;
  pairExp[pos] = e;
  posOf[i] = pos;
}

__global__ void padfill_kernel(const int* __restrict__ cnt, const int* __restrict__ offA,
                               int* __restrict__ pairTok, int* __restrict__ pairExp) {
  int e = blockIdx.x;
  int start = offA[e] + cnt[e];
  int end = offA[e + 1];
  for (int i = start + threadIdx.x; i < end; i += 256) {
    pairTok[i] = 0;
    pairExp[i] = e;
  }
}

// ---------------- combine top-2 expert outputs ----------------
__global__ void combine_kernel(const u16* __restrict__ eo, const int* __restrict__ posOf,
                               const float* __restrict__ wts, u16* __restrict__ comb) {
  int t = blockIdx.x, d = threadIdx.x;
  int p0 = posOf[t * 2], p1 = posOf[t * 2 + 1];
  float w0 = wts[t * 2], w1 = wts[t * 2 + 1];
  float v = w0 * b2f(eo[(size_t)p0 * 256 + d]) + w1 * b2f(eo[(size_t)p1 * 256 + d]);
  comb[(size_t)t * 256 + d] = f2b(v);
}

// ---------------- load-balance loss (f32 out) ----------------
__global__ void lbloss_kernel(const float* __restrict__ probs, const int* __restrict__ cnt,
                              float* __restrict__ outp) {
  __shared__ float red[256];
  int t = threadIdx.x;
  float pl[8];
#pragma unroll
  for (int e = 0; e < 8; ++e) pl[e] = 0.f;
  for (int i = t; i < 8192; i += 256) {
#pragma unroll
    for (int e = 0; e < 8; ++e) pl[e] += probs[(size_t)i * 8 + e];
  }
  float P[8];
  for (int e = 0; e < 8; ++e) {
    red[t] = pl[e];
    __syncthreads();
    for (int s = 128; s > 0; s >>= 1) {
      if (t < s) red[t] += red[t + s];
      __syncthreads();
    }
    P[e] = red[0] / 8192.f;
    __syncthreads();
  }
  if (t == 0) {
    float imp = 0.f, ent = 0.f;
    for (int e = 0; e < 8; ++e) {
      float f = (float)cnt[e] / 8192.f;
      imp += f * P[e];
      ent -= P[e] * logf(P[e] + 1e-8f);
    }
    imp *= 8.f;
    float maxent = logf(8.f);
    outp[0] = (imp + (maxent - ent) / maxent) * 0.01f;
  }
}

// =========================================================================
extern "C" void kernel_launch(void* const* d_in, const int* in_sizes, int n_in,
                              void* d_out, int out_size, void* d_ws, size_t ws_size,
                              hipStream_t stream) {
  const float* id_emb   = (const float*)d_in[0];
  const float* content  = (const float*)d_in[1];
  const float* collab   = (const float*)d_in[2];
  const float* ln_ct_g  = (const float*)d_in[3];
  const float* ln_ct_b  = (const float*)d_in[4];
  const float* ln_cb_g  = (const float*)d_in[5];
  const float* ln_cb_b  = (const float*)d_in[6];
  const float* Wc       = (const float*)d_in[7];
  const float* bc       = (const float*)d_in[8];
  const float* Wcb      = (const float*)d_in[9];
  const float* bcb      = (const float*)d_in[10];
  const float* Wg1      = (const float*)d_in[11];
  const float* bg1      = (const float*)d_in[12];
  const float* lng_g    = (const float*)d_in[13];
  const float* lng_b    = (const float*)d_in[14];
  const float* Wg2      = (const float*)d_in[15];
  const float* bg2      = (const float*)d_in[16];
  const float* Wg3      = (const float*)d_in[17];
  const float* bg3      = (const float*)d_in[18];
  const float* We1      = (const float*)d_in[19];
  const float* be1      = (const float*)d_in[20];
  const float* lne1_g   = (const float*)d_in[21];
  const float* lne1_b   = (const float*)d_in[22];
  const float* We2      = (const float*)d_in[23];
  const float* be2      = (const float*)d_in[24];
  const float* We3      = (const float*)d_in[25];
  const float* be3      = (const float*)d_in[26];
  const float* lne3_g   = (const float*)d_in[27];
  const float* lne3_b   = (const float*)d_in[28];
  const float* Wout     = (const float*)d_in[29];
  const float* bout     = (const float*)d_in[30];
  const float* alpha    = (const float*)d_in[31];
  (void)in_sizes; (void)n_in; (void)out_size; (void)ws_size;

  float* out = (float*)d_out;  // f32: 8388608 fused + 1 lb_loss
  char* ws = (char*)d_ws;
  size_t o = 0;
  auto AL = [&](size_t bytes) {
    size_t r = o;
    o += (bytes + 255) & ~(size_t)255;
    return r;
  };

  u16* WcT   = (u16*)(ws + AL(1024ull * 768 * 2));
  u16* WcbT  = (u16*)(ws + AL(1024ull * 64 * 2));
  u16* Wg1T  = (u16*)(ws + AL(1536ull * 3072 * 2));
  u16* Wg2T  = (u16*)(ws + AL(768ull * 1536 * 2));
  u16* We1T  = (u16*)(ws + AL(8ull * 1024 * 3072 * 2));
  u16* We2T  = (u16*)(ws + AL(8ull * 512 * 1024 * 2));
  u16* We3T  = (u16*)(ws + AL(8ull * 256 * 512 * 2));
  u16* WoutT = (u16*)(ws + AL(1024ull * 256 * 2));
  u16* xb3   = (u16*)(ws + AL(8192ull * 3072 * 2));
  size_t R1  = AL(17408ull * 1024 * 2);  // ct_norm|cb_norm -> g1 -> h1
  u16* ct_norm = (u16*)(ws + R1);
  u16* cb_norm = (u16*)(ws + R1 + 8192ull * 768 * 2);
  u16* g1      = (u16*)(ws + R1);
  u16* h1      = (u16*)(ws + R1);
  size_t R2  = AL(17408ull * 512 * 2);   // g2 -> h2
  u16* g2 = (u16*)(ws + R2);
  u16* h2 = (u16*)(ws + R2);
  u16* eo   = (u16*)(ws + AL(17408ull * 256 * 2));
  u16* comb = (u16*)(ws + AL(8192ull * 256 * 2));
  float* probs = (float*)(ws + AL(8192ull * 8 * 4));
  int* topi    = (int*)(ws + AL(8192ull * 2 * 4));
  float* wts   = (float*)(ws + AL(8192ull * 2 * 4));
  int* posOf   = (int*)(ws + AL(8192ull * 2 * 4));
  int* pairTok = (int*)(ws + AL(17408ull * 4));
  int* pairExp = (int*)(ws + AL(17408ull * 4));
  int* cnt     = (int*)(ws + AL(64));
  int* offA    = (int*)(ws + AL(64));
  int* cursor  = (int*)(ws + AL(64));

  // ---- batched weight prepack (1 launch, 9136 tiles) ----
  PackTable tab;
  auto mk = [](const float* s, u16* d, int K, int M, int z) {
    PackDesc p;
    p.src = s; p.dst = d; p.K = K; p.M = M;
    p.tx = M / 64; p.tilesPerMat = (M / 64) * (K / 64); p.base = 0;
    return p;  // base filled below; z folded via total tiles = tilesPerMat*z
  };
  PackDesc descs[8] = {
      mk(Wc, WcT, 768, 1024, 1),    mk(Wcb, WcbT, 64, 1024, 1),
      mk(Wg1, Wg1T, 3072, 1536, 1), mk(Wg2, Wg2T, 1536, 768, 1),
      mk(We1, We1T, 3072, 1024, 8), mk(We2, We2T, 1024, 512, 8),
      mk(We3, We3T, 512, 256, 8),   mk(Wout, WoutT, 256, 1024, 1)};
  int zcount[8] = {1, 1, 1, 1, 8, 8, 8, 1};
  int base = 0;
  for (int i = 0; i < 8; ++i) {
    descs[i].base = base;
    base += descs[i].tilesPerMat * zcount[i];
  }
  for (int i = 0; i < 8; ++i) tab.d[i] = descs[i];
  tab.total = base;  // 9136
  prepack_all<<<base, 256, 0, stream>>>(tab);

  // ---- input LN + build xb3 = [id | ct_proj | cb_proj] ----
  ln_rows<768, false, false, float><<<8192, 256, 0, stream>>>(content, ct_norm, ln_ct_g, ln_ct_b, nullptr, nullptr);
  ln_rows<64, false, false, float><<<8192, 64, 0, stream>>>(collab, cb_norm, ln_cb_g, ln_cb_b, nullptr, nullptr);
  copy_id3<<<4096, 256, 0, stream>>>(id_emb, xb3);
  gemm_bf<0, false, false><<<dim3(64, 8), 256, 0, stream>>>(
      ct_norm, WcT, bc, xb3 + 1024, nullptr, 768, 768, 3072,
      0, 0, nullptr, nullptr, nullptr, nullptr);
  gemm_bf<0, false, false><<<dim3(64, 8), 256, 0, stream>>>(
      cb_norm, WcbT, bcb, xb3 + 2048, nullptr, 64, 64, 3072,
      0, 0, nullptr, nullptr, nullptr, nullptr);

  // ---- router MLP ----
  gemm_bf<0, false, false><<<dim3(64, 12), 256, 0, stream>>>(
      xb3, Wg1T, bg1, g1, nullptr, 3072, 3072, 1536,
      0, 0, nullptr, nullptr, nullptr, nullptr);
  ln_rows<1536, true, false, u16><<<8192, 256, 0, stream>>>(g1, g1, lng_g, lng_b, nullptr, nullptr);
  gemm_bf<1, false, false><<<dim3(64, 6), 256, 0, stream>>>(
      g1, Wg2T, bg2, g2, nullptr, 1536, 1536, 768,
      0, 0, nullptr, nullptr, nullptr, nullptr);
  router_kernel<<<2048, 256, 0, stream>>>(g2, Wg3, bg3, probs, topi, wts);

  // ---- routing lists ----
  count_kernel<<<1, 256, 0, stream>>>(topi, cnt, offA, cursor);
  scatter_kernel<<<64, 256, 0, stream>>>(topi, cursor, pairTok, pairExp, posOf);
  padfill_kernel<<<8, 256, 0, stream>>>(cnt, offA, pairTok, pairExp);

  // ---- experts (top-2 grouped) ----
  gemm_bf<0, true, true><<<dim3(136, 8), 256, 0, stream>>>(
      xb3, We1T, be1, h1, nullptr, 3072, 3072, 1024,
      3072l * 1024, 1024, offA, pairTok, nullptr, nullptr);
  ln_rows<1024, true, true, u16><<<17408, 256, 0, stream>>>(h1, h1, lne1_g, lne1_b, pairExp, offA + 8);
  gemm_bf<1, true, false><<<dim3(136, 4), 256, 0, stream>>>(
      h1, We2T, be2, h2, nullptr, 1024, 1024, 512,
      512l * 1024, 512, offA, nullptr, nullptr, nullptr);
  gemm_bf<0, true, false><<<dim3(136, 2), 256, 0, stream>>>(
      h2, We3T, be3, eo, nullptr, 512, 512, 256,
      256l * 512, 256, offA, nullptr, nullptr, nullptr);
  ln_rows<256, false, true, u16><<<17408, 256, 0, stream>>>(eo, eo, lne3_g, lne3_b, pairExp, offA + 8);
  combine_kernel<<<8192, 256, 0, stream>>>(eo, posOf, wts, comb);

  // ---- output projection + alpha-residual -> f32 out ----
  gemm_bf<2, false, false><<<dim3(64, 8), 256, 0, stream>>>(
      comb, WoutT, bout, nullptr, out, 256, 256, 1024,
      0, 0, nullptr, nullptr, id_emb, alpha);

  // ---- load-balance loss (f32) ----
  lbloss_kernel<<<1, 256, 0, stream>>>(probs, cnt, out + 8388608);
}

// Round 18
// 627.579 us; speedup vs baseline: 1.1886x; 1.0267x over previous
//
#include <hip/hip_runtime.h>
#include <hip/hip_bf16.h>

using u16 = unsigned short;
typedef float f32x4 __attribute__((ext_vector_type(4)));
typedef short short8 __attribute__((ext_vector_type(8)));
typedef unsigned short ushort8 __attribute__((ext_vector_type(8)));

typedef __attribute__((address_space(1))) const unsigned int gu32;
typedef __attribute__((address_space(3))) unsigned int lu32;

__device__ __forceinline__ float b2f(u16 u) {
  unsigned v = ((unsigned)u) << 16;
  float f;
  __builtin_memcpy(&f, &v, 4);
  return f;
}
__device__ __forceinline__ u16 f2b(float f) {
  unsigned u;
  __builtin_memcpy(&u, &f, 4);
  unsigned r = (u + 0x7fffu + ((u >> 16) & 1u)) >> 16;
  return (u16)r;
}
__device__ __forceinline__ float ldv(float x) { return x; }
__device__ __forceinline__ float ldv(u16 x) { return b2f(x); }

__device__ __forceinline__ void gl_lds16(const void* g, void* l) {
  __builtin_amdgcn_global_load_lds((gu32*)g, (lu32*)l, 16, 0, 0);
}

// ---------------- row LayerNorm; input f32 or bf16, params f32, out bf16 -------
template <int D, bool RELU, bool PEREXP, typename TIN>
__global__ void ln_rows(const TIN* __restrict__ in, u16* __restrict__ out,
                        const float* __restrict__ gamma, const float* __restrict__ beta,
                        const int* __restrict__ pairExp, const int* __restrict__ total) {
  constexpr int T = (D >= 256) ? 256 : 64;
  constexpr int VPT = D / T;
  int row = blockIdx.x;
  if constexpr (PEREXP) {
    if (row >= *total) return;
  }
  int t = threadIdx.x;
  const TIN* r = in + (size_t)row * D;
  float vals[VPT];
  float s = 0.f, ss = 0.f;
#pragma unroll
  for (int i = 0; i < VPT; ++i) {
    float v = ldv(r[t + i * T]);
    vals[i] = v;
    s += v;
    ss += v * v;
  }
#pragma unroll
  for (int m = 1; m < 64; m <<= 1) {
    s += __shfl_xor(s, m);
    ss += __shfl_xor(ss, m);
  }
  if constexpr (T == 256) {
    __shared__ float red[8];
    int wave = t >> 6, lane = t & 63;
    if (lane == 0) { red[wave] = s; red[4 + wave] = ss; }
    __syncthreads();
    s = red[0] + red[1] + red[2] + red[3];
    ss = red[4] + red[5] + red[6] + red[7];
  }
  float mean = s / (float)D;
  float var = ss / (float)D - mean * mean;
  var = fmaxf(var, 0.f);
  float rstd = 1.f / sqrtf(var + 1e-5f);
  const float* g = gamma;
  const float* b = beta;
  if constexpr (PEREXP) {
    int e = pairExp[row];
    g += (size_t)e * D;
    b += (size_t)e * D;
  }
  u16* o = out + (size_t)row * D;
#pragma unroll
  for (int i = 0; i < VPT; ++i) {
    int idx = t + i * T;
    float v = (vals[i] - mean) * rstd * g[idx] + b[idx];
    if constexpr (RELU) v = fmaxf(v, 0.f);
    o[idx] = f2b(v);
  }
}

// ---------------- LN for D=64, 4 rows per 256-thread block ----------------
__global__ void ln_rows64(const float* __restrict__ in, u16* __restrict__ out,
                          const float* __restrict__ gamma, const float* __restrict__ beta) {
  int row = blockIdx.x * 4 + (threadIdx.x >> 6);
  int lane = threadIdx.x & 63;
  float v = in[(size_t)row * 64 + lane];
  float s = v, q = v * v;
#pragma unroll
  for (int m = 1; m < 64; m <<= 1) {
    s += __shfl_xor(s, m);
    q += __shfl_xor(q, m);
  }
  float mean = s / 64.f;
  float var = fmaxf(q / 64.f - mean * mean, 0.f);
  float rstd = 1.f / sqrtf(var + 1e-5f);
  out[(size_t)row * 64 + lane] = f2b((v - mean) * rstd * gamma[lane] + beta[lane]);
}

// ---------------- batched prepack: all weights f32 [K][M] -> bf16 [M][K] --------
struct PackDesc {
  const float* src;
  u16* dst;
  int K, M, tx, tilesPerMat, base;
};
struct PackTable { PackDesc d[8]; int total; };

__global__ void prepack_all(PackTable tab) {
  int bid = blockIdx.x;
  int w = 0;
#pragma unroll
  for (int i = 1; i < 8; ++i)
    if (bid >= tab.d[i].base) w = i;
  PackDesc pd = tab.d[w];
  int local = bid - pd.base;
  int z = local / pd.tilesPerMat;
  int tl = local % pd.tilesPerMat;
  int m0 = (tl % pd.tx) * 64, k0 = (tl / pd.tx) * 64;
  size_t zo = (size_t)z * pd.K * pd.M;
  const float* ip = pd.src + zo;
  u16* op = pd.dst + zo;

  __shared__ u16 tile[64 * 65];
  int t = threadIdx.x;
#pragma unroll
  for (int h = 0; h < 4; ++h) {
    int u = t + h * 256;
    int kr = u >> 4, mc = (u & 15) * 4;
    f32x4 v = *(const f32x4*)(ip + (size_t)(k0 + kr) * pd.M + m0 + mc);
#pragma unroll
    for (int i = 0; i < 4; ++i) tile[kr * 65 + mc + i] = f2b(v[i]);
  }
  __syncthreads();
#pragma unroll
  for (int h = 0; h < 2; ++h) {
    int u = t + h * 256;
    int mr = u >> 3, kc = (u & 7) * 8;
    ushort8 v;
#pragma unroll
    for (int i = 0; i < 8; ++i) v[i] = tile[(kc + i) * 65 + mr];
    *(ushort8*)(op + (size_t)(m0 + mr) * pd.K + k0 + kc) = v;
  }
}

// ---------------- id_emb f32 -> xb3 cols 0..1023 (bf16) ----------------
__global__ void copy_id3(const float* __restrict__ id, u16* __restrict__ xb3) {
  size_t i = ((size_t)blockIdx.x * 256 + threadIdx.x) * 8;
  size_t t = i >> 10, d = i & 1023;
  f32x4 a = *(const f32x4*)(id + i);
  f32x4 b = *(const f32x4*)(id + i + 4);
  ushort8 v;
#pragma unroll
  for (int j = 0; j < 4; ++j) { v[j] = f2b(a[j]); v[j + 4] = f2b(b[j]); }
  *(ushort8*)(xb3 + t * 3072 + d) = v;
}

#define BM 128
#define BN 128
#define BKK 64

// ---------------- GEMM: bf16 A [rows][lda], bf16 Bt [M][K]; BK=64 single-buffer.
// SWZ: XCD-chunked bijective remap (expert GEMMs only; R13: We1 169 vs 177 us).
template <int EPI, bool EXPERT, bool GATHER, bool SWZ>
__global__ __launch_bounds__(256, 3)
void gemm_bf(const u16* __restrict__ A, const u16* __restrict__ Bt,
             const float* __restrict__ bias,
             u16* __restrict__ C, float* __restrict__ Cf,
             int K, int lda, int ldc,
             long strideB, int strideBias,
             const int* __restrict__ offA, const int* __restrict__ pairTok,
             const float* __restrict__ resid, const float* __restrict__ alphaPtr) {
  int rowTile, colTile;
  if constexpr (SWZ) {
    int gy = gridDim.y;
    int nwg = gridDim.x * gy;
    int id = blockIdx.x * gy + blockIdx.y;
    int q = nwg >> 3, r = nwg & 7;
    int xcd = id & 7, pos = id >> 3;
    int nid = (xcd < r) ? (xcd * (q + 1) + pos) : (r * (q + 1) + (xcd - r) * q + pos);
    rowTile = (nid / gy) * BM;
    colTile = (nid % gy) * BN;
  } else {
    rowTile = blockIdx.x * BM;
    colTile = blockIdx.y * BN;
  }
  if constexpr (EXPERT) {
    if (rowTile >= offA[8]) return;
    int e = 0;
    while (rowTile >= offA[e + 1]) ++e;  // <=8 uniform iters
    Bt += (size_t)e * strideB;
    bias += (size_t)e * strideBias;
  }

  __shared__ u16 As[BM * BKK];  // 16 KB
  __shared__ u16 Bs[BN * BKK];  // 16 KB

  int t = threadIdx.x;
  int lane = t & 63;
  int wv = t >> 6;
  int wr = wv >> 1, wc = wv & 1;
  int l15 = lane & 15, l4 = lane >> 4;

  int rowInLane = lane >> 3;
  int colLane = (lane & 7) * 8;
  const u16* aSrc[4];
  const u16* bSrc[4];
  u16* aDst[4];
  u16* bDst[4];
#pragma unroll
  for (int j = 0; j < 4; ++j) {
    int rr = j * 32 + wv * 8 + rowInLane;
    size_t aRow;
    if constexpr (GATHER) {
      aRow = (size_t)pairTok[rowTile + rr] * lda;
    } else {
      aRow = (size_t)(rowTile + rr) * lda;
    }
    aSrc[j] = A + aRow + colLane;
    bSrc[j] = Bt + (size_t)(colTile + rr) * K + colLane;
    aDst[j] = As + (j * 32 + wv * 8) * BKK;
    bDst[j] = Bs + (j * 32 + wv * 8) * BKK;
  }

  f32x4 zero4 = {0.f, 0.f, 0.f, 0.f};
  f32x4 acc[4][4];
#pragma unroll
  for (int m = 0; m < 4; ++m)
#pragma unroll
    for (int n = 0; n < 4; ++n) acc[m][n] = zero4;

  for (int k0 = 0; k0 < K; k0 += BKK) {
    __syncthreads();
#pragma unroll
    for (int j = 0; j < 4; ++j) gl_lds16(aSrc[j] + k0, aDst[j]);
#pragma unroll
    for (int j = 0; j < 4; ++j) gl_lds16(bSrc[j] + k0, bDst[j]);
    asm volatile("s_waitcnt vmcnt(0)" ::: "memory");
    __syncthreads();
    short8 af[4][2];
#pragma unroll
    for (int m = 0; m < 4; ++m)
#pragma unroll
      for (int ks = 0; ks < 2; ++ks)
        af[m][ks] = *(const short8*)&As[(wr * 64 + m * 16 + l15) * BKK + ks * 32 + l4 * 8];
#pragma unroll
    for (int n = 0; n < 4; ++n) {
      short8 bfr[2];
#pragma unroll
      for (int ks = 0; ks < 2; ++ks)
        bfr[ks] = *(const short8*)&Bs[(wc * 64 + n * 16 + l15) * BKK + ks * 32 + l4 * 8];
#pragma unroll
      for (int m = 0; m < 4; ++m)
#pragma unroll
        for (int ks = 0; ks < 2; ++ks)  // ks ascending: bit-identical order
          acc[m][n] = __builtin_amdgcn_mfma_f32_16x16x32_bf16(af[m][ks], bfr[ks], acc[m][n], 0, 0, 0);
    }
  }

  float alphaV = 0.f;
  if constexpr (EPI == 2) alphaV = alphaPtr[0];
#pragma unroll
  for (int n = 0; n < 4; ++n) {
    int col = colTile + wc * 64 + n * 16 + l15;
    float bv = bias[col];
#pragma unroll
    for (int m = 0; m < 4; ++m) {
      int r2 = rowTile + wr * 64 + m * 16 + l4 * 4;
#pragma unroll
      for (int j = 0; j < 4; ++j) {
        float v = acc[m][n][j] + bv;
        if constexpr (EPI == 1) v = fmaxf(v, 0.f);
        if constexpr (EPI == 2) {
          Cf[(size_t)(r2 + j) * ldc + col] =
              resid[(size_t)(r2 + j) * ldc + col] + alphaV * v;
        } else {
          C[(size_t)(r2 + j) * ldc + col] = f2b(v);
        }
      }
    }
  }
}

// ---------------- router: logits -> softmax -> top2 -> weights ----------------
__global__ void router_kernel(const u16* __restrict__ g2, const float* __restrict__ Wg3,
                              const float* __restrict__ bg3, float* __restrict__ probs,
                              int* __restrict__ topi, float* __restrict__ wts) {
  int tok = blockIdx.x * 4 + (threadIdx.x >> 6);
  int lane = threadIdx.x & 63;
  const u16* row = g2 + (size_t)tok * 768;
  float acc[8];
#pragma unroll
  for (int e = 0; e < 8; ++e) acc[e] = 0.f;
  for (int j = lane; j < 768; j += 64) {
    float v = b2f(row[j]);
    f32x4 w0 = *(const f32x4*)(Wg3 + (size_t)j * 8);
    f32x4 w1 = *(const f32x4*)(Wg3 + (size_t)j * 8 + 4);
#pragma unroll
    for (int e = 0; e < 4; ++e) { acc[e] += v * w0[e]; acc[e + 4] += v * w1[e]; }
  }
#pragma unroll
  for (int e = 0; e < 8; ++e) {
#pragma unroll
    for (int m = 1; m < 64; m <<= 1) acc[e] += __shfl_xor(acc[e], m);
  }
  if (lane == 0) {
    float lg[8], mx = -3.4e38f;
#pragma unroll
    for (int e = 0; e < 8; ++e) {
      lg[e] = acc[e] + bg3[e];
      mx = fmaxf(mx, lg[e]);
    }
    float p[8], s = 0.f;
#pragma unroll
    for (int e = 0; e < 8; ++e) {
      p[e] = expf(lg[e] - mx);
      s += p[e];
    }
    float inv = 1.f / s;
#pragma unroll
    for (int e = 0; e < 8; ++e) {
      p[e] *= inv;
      probs[(size_t)tok * 8 + e] = p[e];
    }
    int i0 = 0;
    for (int e = 1; e < 8; ++e)
      if (p[e] > p[i0]) i0 = e;
    int i1 = (i0 == 0) ? 1 : 0;
    for (int e = 0; e < 8; ++e)
      if (e != i0 && p[e] > p[i1]) i1 = e;
    float w0 = p[i0], w1 = p[i1];
    float wsum = w0 + w1 + 1e-8f;
    topi[tok * 2] = i0;
    topi[tok * 2 + 1] = i1;
    wts[tok * 2] = w0 / wsum;
    wts[tok * 2 + 1] = w1 / wsum;
  }
}

// ---------------- routing bookkeeping ----------------
__global__ void count_kernel(const int* __restrict__ topi, int* __restrict__ cnt,
                             int* __restrict__ offA, int* __restrict__ cursor) {
  __shared__ int c[8];
  int t = threadIdx.x;
  if (t < 8) c[t] = 0;
  __syncthreads();
  for (int i = t; i < 16384; i += 256) atomicAdd(&c[topi[i]], 1);
  __syncthreads();
  if (t == 0) {
    int off = 0;
    for (int e = 0; e < 8; ++e) {
      cnt[e] = c[e];
      offA[e] = off;
      cursor[e] = off;
      off += (c[e] + 127) & ~127;
    }
    offA[8] = off;
  }
}

// scatter (blocks 0..63) + padfill (blocks 64..71) in one dispatch
__global__ void scatter_padfill(const int* __restrict__ topi, int* __restrict__ cursor,
                                const int* __restrict__ cnt, const int* __restrict__ offA,
                                int* __restrict__ pairTok, int* __restrict__ pairExp,
                                int* __restrict__ posOf) {
  if (blockIdx.x < 64) {
    int i = blockIdx.x * 256 + threadIdx.x;
    int e = topi[i];
    int pos = atomicAdd(&cursor[e], 1);
    pairTok[pos] = i >> 1;
    pairExp[pos] = e;
    posOf[i] = pos;
  } else {
    int e = blockIdx.x - 64;
    int start = offA[e] + cnt[e];
    int end = offA[e + 1];
    for (int i = start + threadIdx.x; i < end; i += 256) {
      pairTok[i] = 0;
      pairExp[i] = e;
    }
  }
}

// ---------------- fused: per-expert LN(eo rows) + top-2 weighted combine --------
__global__ void combine_ln(const u16* __restrict__ eo, const int* __restrict__ posOf,
                           const int* __restrict__ pairExp, const float* __restrict__ wts,
                           const float* __restrict__ g3, const float* __restrict__ b3,
                           u16* __restrict__ comb) {
  int t = blockIdx.x, d = threadIdx.x;
  int p0 = posOf[t * 2], p1 = posOf[t * 2 + 1];
  float w0 = wts[t * 2], w1 = wts[t * 2 + 1];
  int e0 = pairExp[p0], e1 = pairExp[p1];
  float v0 = b2f(eo[(size_t)p0 * 256 + d]);
  float v1 = b2f(eo[(size_t)p1 * 256 + d]);
  float s0 = v0, q0 = v0 * v0, s1 = v1, q1 = v1 * v1;
#pragma unroll
  for (int m = 1; m < 64; m <<= 1) {
    s0 += __shfl_xor(s0, m);
    q0 += __shfl_xor(q0, m);
    s1 += __shfl_xor(s1, m);
    q1 += __shfl_xor(q1, m);
  }
  __shared__ float rs[4][4];
  int wave = d >> 6, lane = d & 63;
  if (lane == 0) { rs[wave][0] = s0; rs[wave][1] = q0; rs[wave][2] = s1; rs[wave][3] = q1; }
  __syncthreads();
  s0 = rs[0][0] + rs[1][0] + rs[2][0] + rs[3][0];
  q0 = rs[0][1] + rs[1][1] + rs[2][1] + rs[3][1];
  s1 = rs[0][2] + rs[1][2] + rs[2][2] + rs[3][2];
  q1 = rs[0][3] + rs[1][3] + rs[2][3] + rs[3][3];
  float m0 = s0 / 256.f, var0 = fmaxf(q0 / 256.f - m0 * m0, 0.f), r0 = 1.f / sqrtf(var0 + 1e-5f);
  float m1 = s1 / 256.f, var1 = fmaxf(q1 / 256.f - m1 * m1, 0.f), r1 = 1.f / sqrtf(var1 + 1e-5f);
  float n0 = (v0 - m0) * r0 * g3[e0 * 256 + d] + b3[e0 * 256 + d];
  float n1 = (v1 - m1) * r1 * g3[e1 * 256 + d] + b3[e1 * 256 + d];
  comb[(size_t)t * 256 + d] = f2b(w0 * n0 + w1 * n1);
}

// ---------------- load-balance loss (f32 out) ----------------
__global__ void lbloss_kernel(const float* __restrict__ probs, const int* __restrict__ cnt,
                              float* __restrict__ outp) {
  __shared__ float red[256];
  int t = threadIdx.x;
  float pl[8];
#pragma unroll
  for (int e = 0; e < 8; ++e) pl[e] = 0.f;
  for (int i = t; i < 8192; i += 256) {
#pragma unroll
    for (int e = 0; e < 8; ++e) pl[e] += probs[(size_t)i * 8 + e];
  }
  float P[8];
  for (int e = 0; e < 8; ++e) {
    red[t] = pl[e];
    __syncthreads();
    for (int s = 128; s > 0; s >>= 1) {
      if (t < s) red[t] += red[t + s];
      __syncthreads();
    }
    P[e] = red[0] / 8192.f;
    __syncthreads();
  }
  if (t == 0) {
    float imp = 0.f, ent = 0.f;
    for (int e = 0; e < 8; ++e) {
      float f = (float)cnt[e] / 8192.f;
      imp += f * P[e];
      ent -= P[e] * logf(P[e] + 1e-8f);
    }
    imp *= 8.f;
    float maxent = logf(8.f);
    outp[0] = (imp + (maxent - ent) / maxent) * 0.01f;
  }
}

// =========================================================================
extern "C" void kernel_launch(void* const* d_in, const int* in_sizes, int n_in,
                              void* d_out, int out_size, void* d_ws, size_t ws_size,
                              hipStream_t stream) {
  const float* id_emb   = (const float*)d_in[0];
  const float* content  = (const float*)d_in[1];
  const float* collab   = (const float*)d_in[2];
  const float* ln_ct_g  = (const float*)d_in[3];
  const float* ln_ct_b  = (const float*)d_in[4];
  const float* ln_cb_g  = (const float*)d_in[5];
  const float* ln_cb_b  = (const float*)d_in[6];
  const float* Wc       = (const float*)d_in[7];
  const float* bc       = (const float*)d_in[8];
  const float* Wcb      = (const float*)d_in[9];
  const float* bcb      = (const float*)d_in[10];
  const float* Wg1      = (const float*)d_in[11];
  const float* bg1      = (const float*)d_in[12];
  const float* lng_g    = (const float*)d_in[13];
  const float* lng_b    = (const float*)d_in[14];
  const float* Wg2      = (const float*)d_in[15];
  const float* bg2      = (const float*)d_in[16];
  const float* Wg3      = (const float*)d_in[17];
  const float* bg3      = (const float*)d_in[18];
  const float* We1      = (const float*)d_in[19];
  const float* be1      = (const float*)d_in[20];
  const float* lne1_g   = (const float*)d_in[21];
  const float* lne1_b   = (const float*)d_in[22];
  const float* We2      = (const float*)d_in[23];
  const float* be2      = (const float*)d_in[24];
  const float* We3      = (const float*)d_in[25];
  const float* be3      = (const float*)d_in[26];
  const float* lne3_g   = (const float*)d_in[27];
  const float* lne3_b   = (const float*)d_in[28];
  const float* Wout     = (const float*)d_in[29];
  const float* bout     = (const float*)d_in[30];
  const float* alpha    = (const float*)d_in[31];
  (void)in_sizes; (void)n_in; (void)out_size; (void)ws_size;

  float* out = (float*)d_out;  // f32: 8388608 fused + 1 lb_loss
  char* ws = (char*)d_ws;
  size_t o = 0;
  auto AL = [&](size_t bytes) {
    size_t r = o;
    o += (bytes + 255) & ~(size_t)255;
    return r;
  };

  u16* WcT   = (u16*)(ws + AL(1024ull * 768 * 2));
  u16* WcbT  = (u16*)(ws + AL(1024ull * 64 * 2));
  u16* Wg1T  = (u16*)(ws + AL(1536ull * 3072 * 2));
  u16* Wg2T  = (u16*)(ws + AL(768ull * 1536 * 2));
  u16* We1T  = (u16*)(ws + AL(8ull * 1024 * 3072 * 2));
  u16* We2T  = (u16*)(ws + AL(8ull * 512 * 1024 * 2));
  u16* We3T  = (u16*)(ws + AL(8ull * 256 * 512 * 2));
  u16* WoutT = (u16*)(ws + AL(1024ull * 256 * 2));
  u16* xb3   = (u16*)(ws + AL(8192ull * 3072 * 2));
  size_t R1  = AL(17408ull * 1024 * 2);  // ct_norm|cb_norm -> g1 -> h1
  u16* ct_norm = (u16*)(ws + R1);
  u16* cb_norm = (u16*)(ws + R1 + 8192ull * 768 * 2);
  u16* g1      = (u16*)(ws + R1);
  u16* h1      = (u16*)(ws + R1);
  size_t R2  = AL(17408ull * 512 * 2);   // g2 -> h2
  u16* g2 = (u16*)(ws + R2);
  u16* h2 = (u16*)(ws + R2);
  u16* eo   = (u16*)(ws + AL(17408ull * 256 * 2));
  u16* comb = (u16*)(ws + AL(8192ull * 256 * 2));
  float* probs = (float*)(ws + AL(8192ull * 8 * 4));
  int* topi    = (int*)(ws + AL(8192ull * 2 * 4));
  float* wts   = (float*)(ws + AL(8192ull * 2 * 4));
  int* posOf   = (int*)(ws + AL(8192ull * 2 * 4));
  int* pairTok = (int*)(ws + AL(17408ull * 4));
  int* pairExp = (int*)(ws + AL(17408ull * 4));
  int* cnt     = (int*)(ws + AL(64));
  int* offA    = (int*)(ws + AL(64));
  int* cursor  = (int*)(ws + AL(64));

  // ---- batched weight prepack (1 launch, 9136 tiles) ----
  PackTable tab;
  auto mk = [](const float* s, u16* d, int K, int M) {
    PackDesc p;
    p.src = s; p.dst = d; p.K = K; p.M = M;
    p.tx = M / 64; p.tilesPerMat = (M / 64) * (K / 64); p.base = 0;
    return p;
  };
  PackDesc descs[8] = {
      mk(Wc, WcT, 768, 1024),    mk(Wcb, WcbT, 64, 1024),
      mk(Wg1, Wg1T, 3072, 1536), mk(Wg2, Wg2T, 1536, 768),
      mk(We1, We1T, 3072, 1024), mk(We2, We2T, 1024, 512),
      mk(We3, We3T, 512, 256),   mk(Wout, WoutT, 256, 1024)};
  int zcount[8] = {1, 1, 1, 1, 8, 8, 8, 1};
  int base = 0;
  for (int i = 0; i < 8; ++i) {
    descs[i].base = base;
    base += descs[i].tilesPerMat * zcount[i];
  }
  for (int i = 0; i < 8; ++i) tab.d[i] = descs[i];
  tab.total = base;
  prepack_all<<<base, 256, 0, stream>>>(tab);

  // ---- input LN + build xb3 = [id | ct_proj | cb_proj] ----
  ln_rows<768, false, false, float><<<8192, 256, 0, stream>>>(content, ct_norm, ln_ct_g, ln_ct_b, nullptr, nullptr);
  ln_rows64<<<2048, 256, 0, stream>>>(collab, cb_norm, ln_cb_g, ln_cb_b);
  copy_id3<<<4096, 256, 0, stream>>>(id_emb, xb3);
  gemm_bf<0, false, false, false><<<dim3(64, 8), 256, 0, stream>>>(
      ct_norm, WcT, bc, xb3 + 1024, nullptr, 768, 768, 3072,
      0, 0, nullptr, nullptr, nullptr, nullptr);
  gemm_bf<0, false, false, false><<<dim3(64, 8), 256, 0, stream>>>(
      cb_norm, WcbT, bcb, xb3 + 2048, nullptr, 64, 64, 3072,
      0, 0, nullptr, nullptr, nullptr, nullptr);

  // ---- router MLP ----
  gemm_bf<0, false, false, false><<<dim3(64, 12), 256, 0, stream>>>(
      xb3, Wg1T, bg1, g1, nullptr, 3072, 3072, 1536,
      0, 0, nullptr, nullptr, nullptr, nullptr);
  ln_rows<1536, true, false, u16><<<8192, 256, 0, stream>>>(g1, g1, lng_g, lng_b, nullptr, nullptr);
  gemm_bf<1, false, false, false><<<dim3(64, 6), 256, 0, stream>>>(
      g1, Wg2T, bg2, g2, nullptr, 1536, 1536, 768,
      0, 0, nullptr, nullptr, nullptr, nullptr);
  router_kernel<<<2048, 256, 0, stream>>>(g2, Wg3, bg3, probs, topi, wts);

  // ---- routing lists ----
  count_kernel<<<1, 256, 0, stream>>>(topi, cnt, offA, cursor);
  scatter_padfill<<<72, 256, 0, stream>>>(topi, cursor, cnt, offA, pairTok, pairExp, posOf);

  // ---- experts (top-2 grouped; SWZ on) ----
  gemm_bf<0, true, true, true><<<dim3(136, 8), 256, 0, stream>>>(
      xb3, We1T, be1, h1, nullptr, 3072, 3072, 1024,
      3072l * 1024, 1024, offA, pairTok, nullptr, nullptr);
  ln_rows<1024, true, true, u16><<<17408, 256, 0, stream>>>(h1, h1, lne1_g, lne1_b, pairExp, offA + 8);
  gemm_bf<1, true, false, true><<<dim3(136, 4), 256, 0, stream>>>(
      h1, We2T, be2, h2, nullptr, 1024, 1024, 512,
      512l * 1024, 512, offA, nullptr, nullptr, nullptr);
  gemm_bf<0, true, false, true><<<dim3(136, 2), 256, 0, stream>>>(
      h2, We3T, be3, eo, nullptr, 512, 512, 256,
      256l * 512, 256, offA, nullptr, nullptr, nullptr);
  combine_ln<<<8192, 256, 0, stream>>>(eo, posOf, pairExp, wts, lne3_g, lne3_b, comb);

  // ---- output projection + alpha-residual -> f32 out ----
  gemm_bf<2, false, false, false><<<dim3(64, 8), 256, 0, stream>>>(
      comb, WoutT, bout, nullptr, out, 256, 256, 1024,
      0, 0, nullptr, nullptr, id_emb, alpha);

  // ---- load-balance loss (f32) ----
  lbloss_kernel<<<1, 256, 0, stream>>>(probs, cnt, out + 8388608);
}